// Round 6
// baseline (338.962 us; speedup 1.0000x reference)
//
#include <hip/hip_runtime.h>

#define B_ 4
#define T_ 4096
#define D_ 1024
#define H_ 8
#define M_ (B_*T_)         // 16384 flat rows

typedef unsigned short u16;
typedef unsigned int u32;
typedef __attribute__((ext_vector_type(8))) short s16x8;
typedef __attribute__((ext_vector_type(4))) float f32x4;

#define LOG2E 1.4426950408889634f
#define SC_AGENT __HIP_MEMORY_SCOPE_AGENT

__device__ __forceinline__ float ex2(float x){
#if __has_builtin(__builtin_amdgcn_exp2f)
  return __builtin_amdgcn_exp2f(x);
#else
  return exp2f(x);
#endif
}
__device__ __forceinline__ float rcpf(float x){
#if __has_builtin(__builtin_amdgcn_rcpf)
  return __builtin_amdgcn_rcpf(x);
#else
  return __fdividef(1.0f, x);
#endif
}
__device__ __forceinline__ float bf2f(u16 u){
  union { u32 i; float f; } v; v.i = ((u32)u) << 16; return v.f;
}
__device__ __forceinline__ u16 f2bf(float f){       // RNE
  union { float f; u32 i; } v; v.f = f;
  u32 i = v.i;
  return (u16)((i + 0x7FFFu + ((i >> 16) & 1u)) >> 16);
}
__device__ __forceinline__ float sigf(float z){     // 1/(1+e^-z)
  return rcpf(1.0f + ex2(-LOG2E * z));
}
__device__ __forceinline__ s16x8 cvt8(float4 a, float4 b){  // fp32x8 -> bf16x8 (trunc)
  s16x8 r;
  r[0] = (short)(__float_as_uint(a.x) >> 16);
  r[1] = (short)(__float_as_uint(a.y) >> 16);
  r[2] = (short)(__float_as_uint(a.z) >> 16);
  r[3] = (short)(__float_as_uint(a.w) >> 16);
  r[4] = (short)(__float_as_uint(b.x) >> 16);
  r[5] = (short)(__float_as_uint(b.y) >> 16);
  r[6] = (short)(__float_as_uint(b.z) >> 16);
  r[7] = (short)(__float_as_uint(b.w) >> 16);
  return r;
}

// ---------------------------------------------------------------- K0
// wt[(mat*8+h)][e][k] = bf16(w_mat[h][k][e])
__global__ __launch_bounds__(256) void k0_transpose(const float* __restrict__ w_in,
                                                    const float* __restrict__ w_a,
                                                    u16* __restrict__ wt){
  __shared__ float ls[128][132];
  const int blk = blockIdx.x;                       // mat*8+h
  const float* src = (blk < 8 ? w_in : w_a) + (size_t)(blk & 7) * 128 * 128;
  u16* dst = wt + (size_t)blk * 128 * 128;
  const int tid = threadIdx.x;
  const int r0 = tid >> 5;          // 0..7
  const int c0 = (tid & 31) * 4;    // 0..124
  #pragma unroll
  for (int it = 0; it < 16; ++it){
    int r = r0 + it * 8;
    *(float4*)(&ls[r][c0]) = *(const float4*)(src + r * 128 + c0);
  }
  __syncthreads();
  #pragma unroll
  for (int it = 0; it < 16; ++it){
    int e = r0 + it * 8;
    ushort4 u;
    u.x = f2bf(ls[c0 + 0][e]);
    u.y = f2bf(ls[c0 + 1][e]);
    u.z = f2bf(ls[c0 + 2][e]);
    u.w = f2bf(ls[c0 + 3][e]);
    *(ushort4*)(dst + e * 128 + c0) = u;
  }
}

// ================================================================ K1 fused
// One block = 128 rows x 64 channels (head h, e-half eh). GEMM (R5 structure)
// + gates + hierarchical in-block scan + ticket-ordered decoupled look-back
// across the 32 blocks of each (batch, h, eh) time chain. Writes y directly.
__global__ __launch_bounds__(256, 2) void k1_fused(
    const float* __restrict__ x, const float* __restrict__ a_param,
    const u16* __restrict__ wt, int* __restrict__ ticket,
    u32* __restrict__ flags, float* __restrict__ aggA,
    float* __restrict__ aggY, float* __restrict__ incV,
    float* __restrict__ y_out, float* __restrict__ hlast)
{
  __shared__ __align__(16) union SMem {
    u16 w[2][64][136];        // W tiles during GEMM (34816 B)
    float y[128 * 68];        // y staging after GEMM (34816 B)
  } SU;
  __shared__ float waveC[4][64][2];   // per-wave 32-row segment per col
  __shared__ float hinS[64];          // incoming prefix per col
  __shared__ float aspS[64];
  __shared__ int vidS;

  const int tid = threadIdx.x;
  if (tid == 0) vidS = atomicAdd(ticket, 1);   // scheduling-ordered virtual id
  __syncthreads();
  const int vid  = vidS;
  const int mbg  = vid >> 4;          // 0..127: global 128-row block (time-major)
  const int hh   = vid & 15;          // h*2+eh
  const int h = hh >> 1, eh = hh & 1;
  const int batch = mbg >> 5;         // 32 row-blocks per batch
  const int link  = mbg & 31;         // position in the scan chain
  const int ch    = batch * 16 + hh;  // chain id (64 chains)
  const int mbase = mbg * 128;
  const int wv = tid >> 6, lane = tid & 63;
  const int q = lane >> 4, l = lane & 15;

  // ---- stage both W tiles (8 loads then 8 LDS writes)
  {
    uint4 wbuf[8];
    #pragma unroll
    for (int it = 0; it < 8; ++it){
      int idx = tid + it * 256;
      int row = idx >> 4;               // mat*64 + e
      int mat = row >> 6, e = row & 63;
      int c8 = (idx & 15) * 8;
      wbuf[it] = *(const uint4*)(wt + (size_t)mat * (8 * 128 * 128)
                                  + (h * 128 + eh * 64 + e) * 128 + c8);
    }
    #pragma unroll
    for (int it = 0; it < 8; ++it){
      int idx = tid + it * 256;
      int row = idx >> 4;
      int c8 = (idx & 15) * 8;
      *(uint4*)(&SU.w[0][0][0] + row * 136 + c8) = wbuf[it];
    }
  }

  // ---- prefetch all A fragments (16 float4 in flight)
  const float* xr0 = x + (size_t)(mbase + wv * 32 + l) * D_ + h * 128;
  const float* xr1 = xr0 + 16 * D_;
  float4 A0[4][2], A1[4][2];
  #pragma unroll
  for (int kb = 0; kb < 4; ++kb){
    int ko = kb * 32 + q * 8;
    A0[kb][0] = *(const float4*)(xr0 + ko);
    A0[kb][1] = *(const float4*)(xr0 + ko + 4);
    A1[kb][0] = *(const float4*)(xr1 + ko);
    A1[kb][1] = *(const float4*)(xr1 + ko + 4);
  }
  if (tid < 64)
    aspS[tid] = 8.0f * log1pf(__expf(a_param[h * 128 + eh * 64 + tid]));
  __syncthreads();

  f32x4 accX[2][4], accG[2][4];
  #pragma unroll
  for (int mt = 0; mt < 2; ++mt)
    #pragma unroll
    for (int nt = 0; nt < 4; ++nt){ accX[mt][nt] = (f32x4)0.0f; accG[mt][nt] = (f32x4)0.0f; }

  #pragma unroll
  for (int kb = 0; kb < 4; ++kb){
    const int ko = kb * 32 + q * 8;
    s16x8 a0 = cvt8(A0[kb][0], A0[kb][1]);
    s16x8 a1 = cvt8(A1[kb][0], A1[kb][1]);
    #pragma unroll
    for (int nt = 0; nt < 4; ++nt){
      s16x8 bi = *(const s16x8*)(&SU.w[0][nt * 16 + l][ko]);
      s16x8 ba = *(const s16x8*)(&SU.w[1][nt * 16 + l][ko]);
      accX[0][nt] = __builtin_amdgcn_mfma_f32_16x16x32_bf16(a0, bi, accX[0][nt], 0, 0, 0);
      accX[1][nt] = __builtin_amdgcn_mfma_f32_16x16x32_bf16(a1, bi, accX[1][nt], 0, 0, 0);
      accG[0][nt] = __builtin_amdgcn_mfma_f32_16x16x32_bf16(a0, ba, accG[0][nt], 0, 0, 0);
      accG[1][nt] = __builtin_amdgcn_mfma_f32_16x16x32_bf16(a1, ba, accG[1][nt], 0, 0, 0);
    }
  }

  // ---- gates -> (a,b) per element. C/D: col=lane&15, row=(lane>>4)*4+reg.
  float av[2][4][4], bv[2][4][4];
  #pragma unroll
  for (int mt = 0; mt < 2; ++mt){
    #pragma unroll
    for (int nt = 0; nt < 4; ++nt){
      const int el = nt * 16 + l;
      const int col = eh * 64 + el;
      const float asp = aspS[el];
      #pragma unroll
      for (int r = 0; r < 4; ++r){
        const int row = wv * 32 + mt * 16 + q * 4 + r;
        float gx = sigf(accX[mt][nt][r]);
        float ga = sigf(accG[mt][nt][r]);
        float la = -asp * ga;                       // (-0.105, 0)
        float a  = ex2(LOG2E * la);
        float mult = sqrtf(fmaxf(1.0f - a * a, 0.0f));
        float xv = x[(size_t)(mbase + row) * D_ + h * 128 + col];  // L2-hot
        av[mt][nt][r] = a;
        bv[mt][nt][r] = mult * gx * xv;
      }
    }
  }

  // ---- in-block scan hierarchy.
  // Segment compose (earlier E, later L): A = E.A*L.A ; Y = L.A*E.Y + L.Y
  float preA[2][4], preY[2][4];       // exclusive prefix within wave, at thread's first row
  #pragma unroll
  for (int nt = 0; nt < 4; ++nt){
    const int col = nt * 16 + l;
    float S0A = 1.0f, S0Y = 0.0f;     // chunk(mt=0) total
    #pragma unroll
    for (int mt = 0; mt < 2; ++mt){
      float a0 = av[mt][nt][0], a1 = av[mt][nt][1], a2 = av[mt][nt][2], a3 = av[mt][nt][3];
      float b0 = bv[mt][nt][0], b1 = bv[mt][nt][1], b2 = bv[mt][nt][2], b3 = bv[mt][nt][3];
      float TA = (a0 * a1) * (a2 * a3);
      float TY = fmaf(a3, fmaf(a2, fmaf(a1, b0, b1), b2), b3);
      // gather the 4 quad segments of this wave
      float QA0 = __shfl(TA, l,      64), QY0 = __shfl(TY, l,      64);
      float QA1 = __shfl(TA, l + 16, 64), QY1 = __shfl(TY, l + 16, 64);
      float QA2 = __shfl(TA, l + 32, 64), QY2 = __shfl(TY, l + 32, 64);
      float QA3 = __shfl(TA, l + 48, 64), QY3 = __shfl(TY, l + 48, 64);
      float P1A = QA0,       P1Y = QY0;
      float P2A = P1A * QA1, P2Y = fmaf(QA1, P1Y, QY1);
      float P3A = P2A * QA2, P3Y = fmaf(QA2, P2Y, QY2);
      float QpA = (q == 0) ? 1.0f : ((q == 1) ? P1A : ((q == 2) ? P2A : P3A));
      float QpY = (q == 0) ? 0.0f : ((q == 1) ? P1Y : ((q == 2) ? P2Y : P3Y));
      float S16A = P3A * QA3, S16Y = fmaf(QA3, P3Y, QY3);
      float MA = (mt == 0) ? 1.0f : S0A;
      float MY = (mt == 0) ? 0.0f : S0Y;
      preA[mt][nt] = MA * QpA;
      preY[mt][nt] = fmaf(QpA, MY, QpY);
      if (mt == 0){ S0A = S16A; S0Y = S16Y; }
      else {
        float WA = S0A * S16A, WY = fmaf(S16A, S0Y, S16Y);   // wave 32-row segment
        if (lane < 16){ waveC[wv][col][0] = WA; waveC[wv][col][1] = WY; }
      }
    }
  }
  __syncthreads();

  // ---- wave-exclusive prefixes (waves < wv), per col
  float wpA[4], wpY[4];
  #pragma unroll
  for (int nt = 0; nt < 4; ++nt){
    int col = nt * 16 + l;
    float A = 1.0f, Y = 0.0f;
    #pragma unroll
    for (int w2 = 0; w2 < 3; ++w2){
      if (w2 < wv){
        float cA = waveC[w2][col][0], cY = waveC[w2][col][1];
        Y = fmaf(cA, Y, cY);
        A = A * cA;
      }
    }
    wpA[nt] = A; wpY[nt] = Y;
  }

  // ---- wave 0: publish aggregate, decoupled look-back, publish prefix
  if (wv == 0){
    const int col = lane;
    float c0A = waveC[0][col][0], c0Y = waveC[0][col][1];
    float c1A = waveC[1][col][0], c1Y = waveC[1][col][1];
    float c2A = waveC[2][col][0], c2Y = waveC[2][col][1];
    float c3A = waveC[3][col][0], c3Y = waveC[3][col][1];
    float bA = c0A * c1A,  bY = fmaf(c1A, c0Y, c1Y);
    bY = fmaf(c2A, bY, c2Y); bA *= c2A;
    bY = fmaf(c3A, bY, c3Y); bA *= c3A;
    float hprev = 0.0f;
    const int base = (ch * 32 + link) * 64 + col;
    if (link > 0){
      __hip_atomic_store(&aggA[base], bA, __ATOMIC_RELAXED, SC_AGENT);
      __hip_atomic_store(&aggY[base], bY, __ATOMIC_RELAXED, SC_AGENT);
      if (lane == 0)
        __hip_atomic_store(&flags[ch * 32 + link], 1u, __ATOMIC_RELEASE, SC_AGENT);
      float acA = 1.0f, acY = 0.0f;   // segment (j, link-1]
      int j = link - 1;
      while (true){
        u32 f;
        do {
          f = __hip_atomic_load(&flags[ch * 32 + j], __ATOMIC_ACQUIRE, SC_AGENT);
          if (f == 0) __builtin_amdgcn_s_sleep(2);
        } while (f == 0);
        const int cj = (ch * 32 + j) * 64 + col;
        if (f == 2u){
          float hj = __hip_atomic_load(&incV[cj], __ATOMIC_RELAXED, SC_AGENT);
          hprev = fmaf(acA, hj, acY);
          break;
        } else {
          float aA = __hip_atomic_load(&aggA[cj], __ATOMIC_RELAXED, SC_AGENT);
          float aY = __hip_atomic_load(&aggY[cj], __ATOMIC_RELAXED, SC_AGENT);
          acY = fmaf(acA, aY, acY);   // seg_j is earlier than acc
          acA = acA * aA;
          --j;
        }
      }
    }
    float hout = fmaf(bA, hprev, bY);
    __hip_atomic_store(&incV[base], hout, __ATOMIC_RELAXED, SC_AGENT);
    if (lane == 0)
      __hip_atomic_store(&flags[ch * 32 + link], 2u, __ATOMIC_RELEASE, SC_AGENT);
    hinS[col] = hprev;
    if (link == 31) hlast[batch * D_ + h * 128 + eh * 64 + col] = hout;
  }
  __syncthreads();

  // ---- final y values -> LDS (aliased over dead W tiles)
  float* yS = SU.y;
  #pragma unroll
  for (int nt = 0; nt < 4; ++nt){
    const int col = nt * 16 + l;
    float h0 = hinS[col];
    float basev = fmaf(wpA[nt], h0, wpY[nt]);     // after waves < wv
    #pragma unroll
    for (int mt = 0; mt < 2; ++mt){
      float v = fmaf(preA[mt][nt], basev, preY[mt][nt]);  // at thread's first row
      const int R0 = wv * 32 + mt * 16 + q * 4;
      #pragma unroll
      for (int r = 0; r < 4; ++r){
        v = fmaf(av[mt][nt][r], v, bv[mt][nt][r]);
        yS[(R0 + r) * 68 + col] = v;
      }
    }
  }
  __syncthreads();

  // ---- coalesced float4 stores
  {
    float* yg = y_out + (size_t)mbase * D_ + h * 128 + eh * 64;
    #pragma unroll
    for (int it = 0; it < 8; ++it){
      int idx = tid + it * 256;
      int row = idx >> 4;
      int c4 = (idx & 15) * 4;
      float4 v = *(float4*)(&yS[row * 68 + c4]);
      *(float4*)(yg + (size_t)row * D_ + c4) = v;
    }
  }
}

extern "C" void kernel_launch(void* const* d_in, const int* in_sizes, int n_in,
                              void* d_out, int out_size, void* d_ws, size_t ws_size,
                              hipStream_t stream) {
  const float* x    = (const float*)d_in[0];
  const float* ap   = (const float*)d_in[1];
  const float* w_in = (const float*)d_in[2];
  const float* w_a  = (const float*)d_in[3];
  float* y = (float*)d_out;                       // 16,777,216 floats
  float* hlast = y + (size_t)B_ * T_ * D_;        // + 4096 floats

  char* ws = (char*)d_ws;
  u16*   wt     = (u16*)(ws);                     //    524,288 B
  u32*   flags  = (u32*)(ws + 524288);            //      8,192 B (64 ch x 32 links)
  int*   ticket = (int*)(ws + 524288 + 8192);     //          4 B
  float* aggA   = (float*)(ws + 540672);          //    524,288 B
  float* aggY   = (float*)(ws + 540672 + 524288); //    524,288 B
  float* incV   = (float*)(ws + 540672 + 1048576);//    524,288 B  (total ~2.1 MB)

  hipMemsetAsync(ws + 524288, 0, 8448, stream);   // zero flags + ticket
  k0_transpose<<<16, 256, 0, stream>>>(w_in, w_a, wt);
  k1_fused<<<2048, 256, 0, stream>>>(x, ap, wt, ticket, flags, aggA, aggY, incV,
                                     y, hlast);
}

// Round 7
// 178.409 us; speedup vs baseline: 1.8999x; 1.8999x over previous
//
#include <hip/hip_runtime.h>

#define B_ 4
#define T_ 4096
#define D_ 1024
#define H_ 8
#define M_ (B_*T_)         // 16384 flat rows

typedef unsigned short u16;
typedef unsigned int u32;
typedef __attribute__((ext_vector_type(8))) short s16x8;
typedef __attribute__((ext_vector_type(4))) float f32x4;

#define LOG2E 1.4426950408889634f

__device__ __forceinline__ float ex2(float x){
#if __has_builtin(__builtin_amdgcn_exp2f)
  return __builtin_amdgcn_exp2f(x);
#else
  return exp2f(x);
#endif
}
__device__ __forceinline__ float rcpf(float x){
#if __has_builtin(__builtin_amdgcn_rcpf)
  return __builtin_amdgcn_rcpf(x);
#else
  return __fdividef(1.0f, x);
#endif
}
__device__ __forceinline__ float bf2f(u16 u){
  union { u32 i; float f; } v; v.i = ((u32)u) << 16; return v.f;
}
__device__ __forceinline__ u16 f2bf(float f){       // RNE
  union { float f; u32 i; } v; v.f = f;
  u32 i = v.i;
  return (u16)((i + 0x7FFFu + ((i >> 16) & 1u)) >> 16);
}
__device__ __forceinline__ float sigf(float z){     // 1/(1+e^-z)
  return rcpf(1.0f + ex2(-LOG2E * z));
}
__device__ __forceinline__ s16x8 cvt8(float4 a, float4 b){  // fp32x8 -> bf16x8 (trunc)
  s16x8 r;
  r[0] = (short)(__float_as_uint(a.x) >> 16);
  r[1] = (short)(__float_as_uint(a.y) >> 16);
  r[2] = (short)(__float_as_uint(a.z) >> 16);
  r[3] = (short)(__float_as_uint(a.w) >> 16);
  r[4] = (short)(__float_as_uint(b.x) >> 16);
  r[5] = (short)(__float_as_uint(b.y) >> 16);
  r[6] = (short)(__float_as_uint(b.z) >> 16);
  r[7] = (short)(__float_as_uint(b.w) >> 16);
  return r;
}

// ---------------------------------------------------------------- K0
// wt[(mat*8+h)][e][k] = bf16(w_mat[h][k][e])
__global__ __launch_bounds__(256) void k0_transpose(const float* __restrict__ w_in,
                                                    const float* __restrict__ w_a,
                                                    u16* __restrict__ wt){
  __shared__ float ls[128][132];
  const int blk = blockIdx.x;                       // mat*8+h
  const float* src = (blk < 8 ? w_in : w_a) + (size_t)(blk & 7) * 128 * 128;
  u16* dst = wt + (size_t)blk * 128 * 128;
  const int tid = threadIdx.x;
  const int r0 = tid >> 5;          // 0..7
  const int c0 = (tid & 31) * 4;    // 0..124
  #pragma unroll
  for (int it = 0; it < 16; ++it){
    int r = r0 + it * 8;
    *(float4*)(&ls[r][c0]) = *(const float4*)(src + r * 128 + c0);
  }
  __syncthreads();
  #pragma unroll
  for (int it = 0; it < 16; ++it){
    int e = r0 + it * 8;
    ushort4 u;
    u.x = f2bf(ls[c0 + 0][e]);
    u.y = f2bf(ls[c0 + 1][e]);
    u.z = f2bf(ls[c0 + 2][e]);
    u.w = f2bf(ls[c0 + 3][e]);
    *(ushort4*)(dst + e * 128 + c0) = u;
  }
}

// ================================================================ K1
// One block = 128 rows x 64 channels (head h, e-half eh). GEMM (R5 structure)
// + gates + in-block hierarchical scan (h_in = 0). Writes packed
// (bf16 y_local | bf16 cumA << 16) coalesced into the d_out region, plus
// per-tile aggregates (A_blk, Y_blk). NO inter-block communication.
__global__ __launch_bounds__(256, 2) void k1_gemm_scan(
    const float* __restrict__ x, const float* __restrict__ a_param,
    const u16* __restrict__ wt, u32* __restrict__ pack,
    float* __restrict__ Ablk, float* __restrict__ Yblk)
{
  __shared__ __align__(16) union SMem {
    u16 w[2][64][136];        // W tiles during GEMM (34816 B)
    u32 p[128 * 68];          // packed staging after GEMM (34816 B)
  } SU;
  __shared__ float waveC[4][64][2];   // per-wave 32-row segment per col
  __shared__ float aspS[64];

  const int blk = blockIdx.x;
  const int hh  = blk & 15;           // h*2+eh
  const int h = hh >> 1, eh = hh & 1;
  const int mbg = blk >> 4;           // global 128-row tile, 0..127
  const int batch = mbg >> 5;
  const int tb    = mbg & 31;         // tile index within batch chain
  const int mbase = mbg * 128;
  const int tid = threadIdx.x;
  const int wv = tid >> 6, lane = tid & 63;
  const int q = lane >> 4, l = lane & 15;

  // ---- stage both W tiles (8 loads then 8 LDS writes)
  {
    uint4 wbuf[8];
    #pragma unroll
    for (int it = 0; it < 8; ++it){
      int idx = tid + it * 256;
      int row = idx >> 4;               // mat*64 + e
      int mat = row >> 6, e = row & 63;
      int c8 = (idx & 15) * 8;
      wbuf[it] = *(const uint4*)(wt + (size_t)mat * (8 * 128 * 128)
                                  + (h * 128 + eh * 64 + e) * 128 + c8);
    }
    #pragma unroll
    for (int it = 0; it < 8; ++it){
      int idx = tid + it * 256;
      int row = idx >> 4;
      int c8 = (idx & 15) * 8;
      *(uint4*)(&SU.w[0][0][0] + row * 136 + c8) = wbuf[it];
    }
  }

  // ---- prefetch all A fragments (16 float4 in flight)
  const float* xr0 = x + (size_t)(mbase + wv * 32 + l) * D_ + h * 128;
  const float* xr1 = xr0 + 16 * D_;
  float4 A0[4][2], A1[4][2];
  #pragma unroll
  for (int kb = 0; kb < 4; ++kb){
    int ko = kb * 32 + q * 8;
    A0[kb][0] = *(const float4*)(xr0 + ko);
    A0[kb][1] = *(const float4*)(xr0 + ko + 4);
    A1[kb][0] = *(const float4*)(xr1 + ko);
    A1[kb][1] = *(const float4*)(xr1 + ko + 4);
  }
  if (tid < 64)
    aspS[tid] = 8.0f * log1pf(__expf(a_param[h * 128 + eh * 64 + tid]));
  __syncthreads();

  f32x4 accX[2][4], accG[2][4];
  #pragma unroll
  for (int mt = 0; mt < 2; ++mt)
    #pragma unroll
    for (int nt = 0; nt < 4; ++nt){ accX[mt][nt] = (f32x4)0.0f; accG[mt][nt] = (f32x4)0.0f; }

  #pragma unroll
  for (int kb = 0; kb < 4; ++kb){
    const int ko = kb * 32 + q * 8;
    s16x8 a0 = cvt8(A0[kb][0], A0[kb][1]);
    s16x8 a1 = cvt8(A1[kb][0], A1[kb][1]);
    #pragma unroll
    for (int nt = 0; nt < 4; ++nt){
      s16x8 bi = *(const s16x8*)(&SU.w[0][nt * 16 + l][ko]);
      s16x8 ba = *(const s16x8*)(&SU.w[1][nt * 16 + l][ko]);
      accX[0][nt] = __builtin_amdgcn_mfma_f32_16x16x32_bf16(a0, bi, accX[0][nt], 0, 0, 0);
      accX[1][nt] = __builtin_amdgcn_mfma_f32_16x16x32_bf16(a1, bi, accX[1][nt], 0, 0, 0);
      accG[0][nt] = __builtin_amdgcn_mfma_f32_16x16x32_bf16(a0, ba, accG[0][nt], 0, 0, 0);
      accG[1][nt] = __builtin_amdgcn_mfma_f32_16x16x32_bf16(a1, ba, accG[1][nt], 0, 0, 0);
    }
  }

  // ---- gates -> (a,b). C/D: col=lane&15, row=(lane>>4)*4+reg.
  float av[2][4][4], bv[2][4][4];
  #pragma unroll
  for (int mt = 0; mt < 2; ++mt){
    #pragma unroll
    for (int nt = 0; nt < 4; ++nt){
      const int el = nt * 16 + l;
      const int col = eh * 64 + el;
      const float asp = aspS[el];
      #pragma unroll
      for (int r = 0; r < 4; ++r){
        const int row = wv * 32 + mt * 16 + q * 4 + r;
        float gx = sigf(accX[mt][nt][r]);
        float ga = sigf(accG[mt][nt][r]);
        float la = -asp * ga;                       // (-0.105, 0)
        float a  = ex2(LOG2E * la);
        float mult = sqrtf(fmaxf(1.0f - a * a, 0.0f));
        float xv = x[(size_t)(mbase + row) * D_ + h * 128 + col];  // L2-hot
        av[mt][nt][r] = a;
        bv[mt][nt][r] = mult * gx * xv;
      }
    }
  }

  // ---- in-block scan hierarchy (verified in R6).
  float preA[2][4], preY[2][4];       // exclusive prefix at thread's first row
  #pragma unroll
  for (int nt = 0; nt < 4; ++nt){
    const int col = nt * 16 + l;
    float S0A = 1.0f, S0Y = 0.0f;
    #pragma unroll
    for (int mt = 0; mt < 2; ++mt){
      float a0 = av[mt][nt][0], a1 = av[mt][nt][1], a2 = av[mt][nt][2], a3 = av[mt][nt][3];
      float b0 = bv[mt][nt][0], b1 = bv[mt][nt][1], b2 = bv[mt][nt][2], b3 = bv[mt][nt][3];
      float TA = (a0 * a1) * (a2 * a3);
      float TY = fmaf(a3, fmaf(a2, fmaf(a1, b0, b1), b2), b3);
      float QA0 = __shfl(TA, l,      64), QY0 = __shfl(TY, l,      64);
      float QA1 = __shfl(TA, l + 16, 64), QY1 = __shfl(TY, l + 16, 64);
      float QA2 = __shfl(TA, l + 32, 64), QY2 = __shfl(TY, l + 32, 64);
      float QA3 = __shfl(TA, l + 48, 64), QY3 = __shfl(TY, l + 48, 64);
      float P1A = QA0,       P1Y = QY0;
      float P2A = P1A * QA1, P2Y = fmaf(QA1, P1Y, QY1);
      float P3A = P2A * QA2, P3Y = fmaf(QA2, P2Y, QY2);
      float QpA = (q == 0) ? 1.0f : ((q == 1) ? P1A : ((q == 2) ? P2A : P3A));
      float QpY = (q == 0) ? 0.0f : ((q == 1) ? P1Y : ((q == 2) ? P2Y : P3Y));
      float S16A = P3A * QA3, S16Y = fmaf(QA3, P3Y, QY3);
      float MA = (mt == 0) ? 1.0f : S0A;
      float MY = (mt == 0) ? 0.0f : S0Y;
      preA[mt][nt] = MA * QpA;
      preY[mt][nt] = fmaf(QpA, MY, QpY);
      if (mt == 0){ S0A = S16A; S0Y = S16Y; }
      else {
        float WA = S0A * S16A, WY = fmaf(S16A, S0Y, S16Y);   // 32-row wave segment
        if (lane < 16){ waveC[wv][col][0] = WA; waveC[wv][col][1] = WY; }
      }
    }
  }
  __syncthreads();

  // ---- wave-exclusive prefixes (waves < wv), per col
  float wpA[4], wpY[4];
  #pragma unroll
  for (int nt = 0; nt < 4; ++nt){
    int col = nt * 16 + l;
    float A = 1.0f, Y = 0.0f;
    #pragma unroll
    for (int w2 = 0; w2 < 3; ++w2){
      if (w2 < wv){
        float cA = waveC[w2][col][0], cY = waveC[w2][col][1];
        Y = fmaf(cA, Y, cY);
        A = A * cA;
      }
    }
    wpA[nt] = A; wpY[nt] = Y;
  }

  // ---- wave 0: publish tile aggregate (no sync with other blocks)
  if (wv == 0){
    const int col = lane;
    float bA = waveC[0][col][0], bY = waveC[0][col][1];
    float cA1 = waveC[1][col][0], cY1 = waveC[1][col][1];
    float cA2 = waveC[2][col][0], cY2 = waveC[2][col][1];
    float cA3 = waveC[3][col][0], cY3 = waveC[3][col][1];
    bY = fmaf(cA1, bY, cY1); bA *= cA1;
    bY = fmaf(cA2, bY, cY2); bA *= cA2;
    bY = fmaf(cA3, bY, cY3); bA *= cA3;
    int gi = (batch * 32 + tb) * D_ + h * 128 + eh * 64 + col;
    Ablk[gi] = bA;
    Yblk[gi] = bY;
  }

  // ---- y_local + cumA per element -> packed LDS (aliased over dead W tiles)
  #pragma unroll
  for (int nt = 0; nt < 4; ++nt){
    const int col = nt * 16 + l;
    float basev = wpY[nt];                         // h_in = 0
    #pragma unroll
    for (int mt = 0; mt < 2; ++mt){
      float v  = fmaf(preA[mt][nt], basev, preY[mt][nt]);
      float cA = wpA[nt] * preA[mt][nt];           // h_in coefficient
      const int R0 = wv * 32 + mt * 16 + q * 4;
      #pragma unroll
      for (int r = 0; r < 4; ++r){
        v  = fmaf(av[mt][nt][r], v, bv[mt][nt][r]);
        cA = cA * av[mt][nt][r];
        SU.p[(R0 + r) * 68 + col] = (u32)f2bf(v) | ((u32)f2bf(cA) << 16);
      }
    }
  }
  __syncthreads();

  // ---- coalesced uint4 stores of packed (y_local, cumA)
  {
    u32* pg = pack + (size_t)mbase * D_ + h * 128 + eh * 64;
    #pragma unroll
    for (int it = 0; it < 8; ++it){
      int idx = tid + it * 256;
      int row = idx >> 4;
      int c4 = (idx & 15) * 4;
      uint4 v = *(uint4*)(&SU.p[row * 68 + c4]);
      *(uint4*)(pg + (size_t)row * D_ + c4) = v;
    }
  }
}

// ------------------------------------- K2: scan 32 tile aggregates per chain
__global__ __launch_bounds__(256) void k2_scan_agg(const float* __restrict__ Ablk,
                                                   const float* __restrict__ Yblk,
                                                   float* __restrict__ hin,
                                                   float* __restrict__ hlast){
  const int g = blockIdx.x * 256 + threadIdx.x;   // 0..4095 channels
  const int batch = g >> 10, d = g & 1023;
  float hcur = 0.0f;
  #pragma unroll
  for (int t = 0; t < 32; ++t){
    int gi = (batch * 32 + t) * D_ + d;
    float A = Ablk[gi], Y = Yblk[gi];
    hin[gi] = hcur;                  // state entering tile t
    hcur = fmaf(A, hcur, Y);
  }
  hlast[batch * D_ + d] = hcur;      // == y[:, -1, :]
}

// --------------------------------- K3: elementwise fixup, in-place over d_out
// y = y_local + cumA * h_in(tile). Pure streaming, no dependencies.
__global__ __launch_bounds__(256) void k3_fixup(const u32* pack,
                                               const float* __restrict__ hin,
                                               float* y_out){
  const int cg = blockIdx.x;          // 0..1023: 16-row group
  const int r0 = cg * 16;
  const int batch = r0 >> 12;
  const int tb = (r0 & (T_ - 1)) >> 7;
  const int d0 = threadIdx.x * 4;
  float4 hv = *(const float4*)(&hin[(batch * 32 + tb) * D_ + d0]);
  #pragma unroll
  for (int t = 0; t < 16; ++t){
    int idx = (r0 + t) * D_ + d0;
    uint4 w = *(const uint4*)(&pack[idx]);
    float4 yv;
    yv.x = fmaf(bf2f((u16)(w.x >> 16)), hv.x, bf2f((u16)(w.x & 0xFFFFu)));
    yv.y = fmaf(bf2f((u16)(w.y >> 16)), hv.y, bf2f((u16)(w.y & 0xFFFFu)));
    yv.z = fmaf(bf2f((u16)(w.z >> 16)), hv.z, bf2f((u16)(w.z & 0xFFFFu)));
    yv.w = fmaf(bf2f((u16)(w.w >> 16)), hv.w, bf2f((u16)(w.w & 0xFFFFu)));
    *(float4*)(&y_out[idx]) = yv;
  }
}

extern "C" void kernel_launch(void* const* d_in, const int* in_sizes, int n_in,
                              void* d_out, int out_size, void* d_ws, size_t ws_size,
                              hipStream_t stream) {
  const float* x    = (const float*)d_in[0];
  const float* ap   = (const float*)d_in[1];
  const float* w_in = (const float*)d_in[2];
  const float* w_a  = (const float*)d_in[3];
  float* y = (float*)d_out;                       // 16,777,216 floats
  float* hlast = y + (size_t)B_ * T_ * D_;        // + 4096 floats
  u32* pack = (u32*)d_out;                        // packed (y_local, cumA) in y region

  char* ws = (char*)d_ws;
  u16*   wt   = (u16*)(ws);                       //    524,288 B
  float* Ablk = (float*)(ws + 524288);            //    524,288 B (4*32*1024)
  float* Yblk = (float*)(ws + 1048576);           //    524,288 B
  float* hin  = (float*)(ws + 1572864);           //    524,288 B  (total ~2.1 MB)

  k0_transpose<<<16, 256, 0, stream>>>(w_in, w_a, wt);
  k1_gemm_scan<<<128 * 16, 256, 0, stream>>>(x, ap, wt, pack, Ablk, Yblk);
  k2_scan_agg<<<16, 256, 0, stream>>>(Ablk, Yblk, hin, hlast);
  k3_fixup<<<1024, 256, 0, stream>>>(pack, hin, y);
}